// Round 4
// baseline (5688.397 us; speedup 1.0000x reference)
//
#include <hip/hip_runtime.h>
#include <hip/hip_bf16.h>
#include <math.h>

typedef unsigned int uint32;
typedef _Float16 h2_t __attribute__((ext_vector_type(2)));

// Problem constants
static constexpr int NX = 32;    // state dim
static constexpr int NU = 8;     // control dim
static constexpr int NA = 24;    // obs dim
static constexpr int NH = 256;   // hidden
static constexpr int NT = 128;   // time steps
static constexpr int NB = 256;   // batch
static constexpr int NXP = NX + 1;   // padded row (bank-conflict fix)
static constexpr float MINV = 0.01f, MAXV = 1.0f, EPSV = 1e-6f;

// Padded head widths (outputs)
static constexpr int H1O = NX*NX + NX*NU + NX;   // 1312 real
static constexpr int H1P = 1344;                 // padded
static constexpr int H2O = NA*NX + NA;           // 792 real
static constexpr int H2P = 800;                  // padded

// Workspace layout in uint32 units (all 16B aligned)
static constexpr size_t OFF_W1 = 0;
static constexpr size_t OFF_W2 = 4096;
static constexpr size_t OFF_H1 = OFF_W2 + 32768;
static constexpr size_t OFF_H2 = OFF_H1 + 172032;
static constexpr size_t OFF_B1 = OFF_H2 + 102400;
static constexpr size_t OFF_B2 = OFF_B1 + 1344;

// ---------------------------------------------------------------------------
__global__ void pack_half_off(const float* __restrict__ src, uint32* __restrict__ dst,
                              int O, int K, int LDP, int off)
{
    int idx = blockIdx.x * blockDim.x + threadIdx.x;
    int K2 = K >> 1;
    if (idx >= O * K2) return;
    int kk = idx % K2;
    int o  = idx / K2;
    int k  = kk * 2;
    int k8 = k >> 3, q = (k >> 1) & 3;
    _Float16 a = (_Float16)src[o * K + k];
    _Float16 b = (_Float16)src[o * K + k + 1];
    uint32 val = (uint32)__builtin_bit_cast(unsigned short, a)
               | ((uint32)__builtin_bit_cast(unsigned short, b) << 16);
    dst[((size_t)k8 * LDP + off + o) * 4 + q] = val;
}

__global__ void pack_bias3(const float* __restrict__ s0, int n0,
                           const float* __restrict__ s1, int n1,
                           const float* __restrict__ s2, int n2,
                           float* __restrict__ dst)
{
    int i = blockIdx.x * blockDim.x + threadIdx.x;
    if (i < n0) dst[i] = s0[i];
    else if (i < n0 + n1) dst[i] = s1[i - n0];
    else if (i < n0 + n1 + n2) dst[i] = s2[i - n0 - n1];
}

// ---------------------------------------------------------------------------
__device__ __forceinline__ float dot2(uint32 w, uint32 x, float acc)
{
#if __has_builtin(__builtin_amdgcn_fdot2)
    return __builtin_amdgcn_fdot2(__builtin_bit_cast(h2_t, w),
                                  __builtin_bit_cast(h2_t, x), acc, false);
#else
    h2_t a = __builtin_bit_cast(h2_t, w), b = __builtin_bit_cast(h2_t, x);
    return acc + (float)a[0] * (float)b[0] + (float)a[1] * (float)b[1];
#endif
}

__device__ __forceinline__ float dot8(uint4 w, uint4 x, float acc)
{
    acc = dot2(w.x, x.x, acc);
    acc = dot2(w.y, x.y, acc);
    acc = dot2(w.z, x.z, acc);
    acc = dot2(w.w, x.w, acc);
    return acc;
}

__device__ __forceinline__ void tri_decode(int p, int& l, int& i)
{
    int lo = (int)((sqrtf(8.f * (float)p + 1.f) - 1.f) * 0.5f);
    while ((lo + 1) * (lo + 2) / 2 <= p) lo++;
    while (lo * (lo + 1) / 2 > p) lo--;
    l = lo;
    i = p - lo * (lo + 1) / 2;
}

__device__ __forceinline__ float sigm_scaled(float z)
{
    return MINV + (MAXV - MINV) / (1.f + expf(-z));
}

__device__ __forceinline__ unsigned short f2h(float v)
{
    _Float16 h = (_Float16)v;
    return __builtin_bit_cast(unsigned short, h);
}

// pack two per-element fp32 values (consecutive tid pairs) into fp16x2 LDS words
__device__ __forceinline__ void pack2_to(int tid, float v0, float v1,
                                         uint32* d0, uint32* d1)
{
    unsigned short u0 = f2h(v0), u1 = f2h(v1);
    int p0 = __shfl_xor((int)u0, 1);
    int p1 = __shfl_xor((int)u1, 1);
    if ((tid & 1) == 0) {
        d0[tid >> 1] = (uint32)u0 | ((uint32)p0 << 16);
        d1[tid >> 1] = (uint32)u1 | ((uint32)p1 << 16);
    }
}

// ---------------------------------------------------------------------------
// One block = 2 batch elements; every weight load feeds 2 dot8s.
__global__ __launch_bounds__(512) void kf_kernel(
    const float* __restrict__ u, const float* __restrict__ a,
    const uint32* __restrict__ wsu,
    const float* __restrict__ b1, const float* __restrict__ b2,
    const float* __restrict__ alpha_p,
    float* __restrict__ out)
{
    const int tid = threadIdx.x;
    const int b0  = blockIdx.x * 2;
    const float alpha = alpha_p[0];

    const uint4* W1h = (const uint4*)(wsu + OFF_W1);
    const uint4* W2h = (const uint4*)(wsu + OFF_W2);
    const uint4* H1h = (const uint4*)(wsu + OFF_H1);
    const uint4* H2h = (const uint4*)(wsu + OFF_H2);
    const float* BH1 = (const float*)(wsu + OFF_B1);
    const float* BH2 = (const float*)(wsu + OFF_B2);

    __shared__ alignas(16) uint32 s_h1h[2][NH / 2];
    __shared__ alignas(16) uint32 s_h2h[2][NH / 2];
    __shared__ alignas(16) uint32 s_qmh[2][NX / 2];
    __shared__ alignas(16) uint32 s_pmh[2][NX / 2];
    __shared__ float s_part[2][2][NH];
    __shared__ float s_Am[2][NX * NXP];
    __shared__ float s_Bm[2][NX * NU];
    __shared__ float s_nx[2][NX];
    __shared__ float s_C[2][NA * NXP];
    __shared__ float s_na[2][NA];
    __shared__ float s_qm[2][NX], s_qc[2][NX * NXP];
    __shared__ float s_pm[2][NX], s_pc[2][NX * NXP];
    __shared__ float s_T2[2][NX * NXP];
    __shared__ float s_T1[2][NA * NXP];
    __shared__ float s_S[2][NA * NA];
    __shared__ float s_Y[2][NA * NX];
    __shared__ float s_innov[2][NA];
    __shared__ float s_a[2][NA], s_u[2][NU];

    const size_t pmO = 0;
    const size_t pcO = (size_t)NT * NB * NX;
    const size_t qmO = pcO + (size_t)NT * NB * NX * NX;
    const size_t qcO = qmO + (size_t)NT * NB * NX;

    for (int t = 0; t < NT; ++t) {
        if (t == 0) {
            if (tid < 64) s_pm[tid >> 5][tid & 31] = 0.f;
            if (tid < 32) s_pmh[tid >> 4][tid & 15] = 0u;
            #pragma unroll
            for (int r = 0; r < 4; r++) {
                int o = tid + 512 * r;         // 2048 logical items
                int e = o >> 10, oo = o & 1023, i = oo >> 5, l = oo & 31;
                s_pc[e][i * NXP + l] = (i == l) ? 1.f : 0.f;
            }
            __syncthreads();
        } else {
            // ===== A1: trunk-W1 on qm (both elems) || store prev qm/qc, load u =====
            if (tid < NH) {
                const uint4* x0 = (const uint4*)s_qmh[0];
                const uint4* x1 = (const uint4*)s_qmh[1];
                float a0 = b1[tid], a1e = b1[tid];
                #pragma unroll
                for (int k8 = 0; k8 < 4; k8++) {
                    uint4 w = W1h[k8 * NH + tid];
                    a0  = dot8(w, x0[k8], a0);
                    a1e = dot8(w, x1[k8], a1e);
                }
                pack2_to(tid, fmaxf(a0, 0.f), fmaxf(a1e, 0.f), s_h1h[0], s_h1h[1]);
            } else {
                int s0 = tid - 256;
                for (int s = s0; s < 2 * (NX + NX * NX); s += 256) {
                    int e  = s >= (NX + NX * NX);
                    int s2 = s - e * (NX + NX * NX);
                    size_t mPrev = (size_t)(t - 1) * NB + b0 + e;
                    if (s2 < NX)
                        __builtin_nontemporal_store(s_qm[e][s2], out + qmO + mPrev * NX + s2);
                    else {
                        int o = s2 - NX, i = o >> 5, l = o & 31;
                        __builtin_nontemporal_store(s_qc[e][i * NXP + l],
                                                    out + qcO + mPrev * NX * NX + o);
                    }
                }
                if (s0 < 2 * NU) {
                    int e = s0 >> 3, j = s0 & 7;
                    s_u[e][j] = u[((size_t)(t - 1) * NB + b0 + e) * NU + j];
                }
            }
            __syncthreads();

            // ===== A2: trunk-W2 split-K =====
            {
                int o = tid & 255, g = tid >> 8;
                const uint4* x0 = (const uint4*)s_h1h[0];
                const uint4* x1 = (const uint4*)s_h1h[1];
                float a0 = 0.f, a1e = 0.f;
                #pragma unroll 4
                for (int k8 = g * 16; k8 < g * 16 + 16; k8++) {
                    uint4 w = W2h[k8 * NH + o];
                    a0  = dot8(w, x0[k8], a0);
                    a1e = dot8(w, x1[k8], a1e);
                }
                s_part[0][g][o] = a0;
                s_part[1][g][o] = a1e;
            }
            __syncthreads();

            // ===== A3: h2 reduce + relu + pack =====
            if (tid < NH) {
                float v0 = fmaxf(s_part[0][0][tid] + s_part[0][1][tid] + b2[tid], 0.f);
                float v1 = fmaxf(s_part[1][0][tid] + s_part[1][1][tid] + b2[tid], 0.f);
                pack2_to(tid, v0, v1, s_h2h[0], s_h2h[1]);
            }
            __syncthreads();

            // ===== A4: head1 (Am | Bm | nx), both elems =====
            {
                const uint4* x0 = (const uint4*)s_h2h[0];
                const uint4* x1 = (const uint4*)s_h2h[1];
                int o0 = tid, o1 = tid + 512, o2 = tid + 1024;
                float bb0 = BH1[o0], bb1 = BH1[o1], bb2 = (tid < 320) ? BH1[o2] : 0.f;
                float acc[2][3] = {{bb0, bb1, bb2}, {bb0, bb1, bb2}};
                #pragma unroll 4
                for (int k8 = 0; k8 < 32; k8++) {
                    uint4 xa = x0[k8], xb = x1[k8];
                    uint4 w0 = H1h[k8 * H1P + o0];
                    acc[0][0] = dot8(w0, xa, acc[0][0]);
                    acc[1][0] = dot8(w0, xb, acc[1][0]);
                    uint4 w1 = H1h[k8 * H1P + o1];
                    acc[0][1] = dot8(w1, xa, acc[0][1]);
                    acc[1][1] = dot8(w1, xb, acc[1][1]);
                    if (tid < 320) {
                        uint4 w2 = H1h[k8 * H1P + o2];
                        acc[0][2] = dot8(w2, xa, acc[0][2]);
                        acc[1][2] = dot8(w2, xb, acc[1][2]);
                    }
                }
                #pragma unroll
                for (int e = 0; e < 2; e++) {
                    #pragma unroll
                    for (int r = 0; r < 3; r++) {
                        if (r == 2 && tid >= 320) break;
                        int o = tid + 512 * r;
                        float v = acc[e][r];
                        if (o < NX * NX) {
                            int i = o >> 5, l = o & 31;
                            s_Am[e][i * NXP + l] = ((i == l) ? 1.f : 0.f) + alpha * v;
                        } else if (o < NX * NX + NX * NU) {
                            s_Bm[e][o - NX * NX] = v;
                        } else if (o < H1O) {
                            s_nx[e][o - (NX * NX + NX * NU)] = sigm_scaled(v);
                        }
                    }
                }
            }
            __syncthreads();

            // ===== A5: T2 = Am@qc ; pm = Am@qm + Bm@u =====
            #pragma unroll
            for (int r = 0; r < 4; r++) {
                int p = tid + 512 * r;       // 2048 items
                int e = p >> 10, o = p & 1023, i = o >> 5, l = o & 31;
                float acc = 0.f;
                #pragma unroll
                for (int j = 0; j < NX; j++)
                    acc = fmaf(s_Am[e][i * NXP + j], s_qc[e][j * NXP + l], acc);
                s_T2[e][i * NXP + l] = acc;
            }
            if (tid < 64) {
                int e = tid >> 5, i = tid & 31;
                float acc = 0.f;
                #pragma unroll
                for (int j = 0; j < NX; j++) acc = fmaf(s_Am[e][i * NXP + j], s_qm[e][j], acc);
                #pragma unroll
                for (int j = 0; j < NU; j++) acc = fmaf(s_Bm[e][i * NU + j], s_u[e][j], acc);
                s_pm[e][i] = acc;
                unsigned short us = f2h(acc);
                int pi = __shfl_xor((int)us, 1);
                if ((tid & 1) == 0) s_pmh[e][i >> 1] = (uint32)us | ((uint32)pi << 16);
            }
            __syncthreads();

            // ===== A6: pc = psd(T2 @ Am^T + diag(nx)) — 1056 items =====
            for (int p = tid; p < 2 * 528; p += 512) {
                int e = p >= 528, pp = p - 528 * e;
                int l, i; tri_decode(pp, l, i);
                float a_il = 0.f, a_li = 0.f;
                #pragma unroll
                for (int j = 0; j < NX; j++) {
                    a_il = fmaf(s_T2[e][i * NXP + j], s_Am[e][l * NXP + j], a_il);
                    a_li = fmaf(s_T2[e][l * NXP + j], s_Am[e][i * NXP + j], a_li);
                }
                if (i == l) {
                    s_pc[e][i * NXP + i] = a_il + s_nx[e][i] + EPSV;
                } else {
                    float v = 0.5f * (a_il + a_li);
                    s_pc[e][i * NXP + l] = v;
                    s_pc[e][l * NXP + i] = v;
                }
            }
            __syncthreads();
        }

        // ===== B1: trunk-W1 on pm || store pm/pc, load a[t] =====
        if (tid < NH) {
            const uint4* x0 = (const uint4*)s_pmh[0];
            const uint4* x1 = (const uint4*)s_pmh[1];
            float a0 = b1[tid], a1e = b1[tid];
            #pragma unroll
            for (int k8 = 0; k8 < 4; k8++) {
                uint4 w = W1h[k8 * NH + tid];
                a0  = dot8(w, x0[k8], a0);
                a1e = dot8(w, x1[k8], a1e);
            }
            pack2_to(tid, fmaxf(a0, 0.f), fmaxf(a1e, 0.f), s_h1h[0], s_h1h[1]);
        } else {
            int s0 = tid - 256;
            for (int s = s0; s < 2 * (NX + NX * NX); s += 256) {
                int e  = s >= (NX + NX * NX);
                int s2 = s - e * (NX + NX * NX);
                size_t mIdx = (size_t)t * NB + b0 + e;
                if (s2 < NX)
                    __builtin_nontemporal_store(s_pm[e][s2], out + pmO + mIdx * NX + s2);
                else {
                    int o = s2 - NX, i = o >> 5, l = o & 31;
                    __builtin_nontemporal_store(s_pc[e][i * NXP + l],
                                                out + pcO + mIdx * NX * NX + o);
                }
            }
            if (s0 < 2 * NA) {
                int e = s0 >= NA, i = s0 - NA * e;
                s_a[e][i] = a[((size_t)t * NB + b0 + e) * NA + i];
            }
        }
        __syncthreads();

        // ===== B2: trunk-W2 split-K =====
        {
            int o = tid & 255, g = tid >> 8;
            const uint4* x0 = (const uint4*)s_h1h[0];
            const uint4* x1 = (const uint4*)s_h1h[1];
            float a0 = 0.f, a1e = 0.f;
            #pragma unroll 4
            for (int k8 = g * 16; k8 < g * 16 + 16; k8++) {
                uint4 w = W2h[k8 * NH + o];
                a0  = dot8(w, x0[k8], a0);
                a1e = dot8(w, x1[k8], a1e);
            }
            s_part[0][g][o] = a0;
            s_part[1][g][o] = a1e;
        }
        __syncthreads();

        // ===== B3: h2 reduce + relu + pack =====
        if (tid < NH) {
            float v0 = fmaxf(s_part[0][0][tid] + s_part[0][1][tid] + b2[tid], 0.f);
            float v1 = fmaxf(s_part[1][0][tid] + s_part[1][1][tid] + b2[tid], 0.f);
            pack2_to(tid, v0, v1, s_h2h[0], s_h2h[1]);
        }
        __syncthreads();

        // ===== B4: head2 (C | na), both elems =====
        {
            const uint4* x0 = (const uint4*)s_h2h[0];
            const uint4* x1 = (const uint4*)s_h2h[1];
            int o0 = tid, o1 = tid + 512;
            float bb0 = BH2[o0], bb1 = (tid < H2P - 512) ? BH2[o1] : 0.f;
            float acc[2][2] = {{bb0, bb1}, {bb0, bb1}};
            #pragma unroll 4
            for (int k8 = 0; k8 < 32; k8++) {
                uint4 xa = x0[k8], xb = x1[k8];
                uint4 w0 = H2h[k8 * H2P + o0];
                acc[0][0] = dot8(w0, xa, acc[0][0]);
                acc[1][0] = dot8(w0, xb, acc[1][0]);
                if (tid < H2P - 512) {
                    uint4 w1 = H2h[k8 * H2P + o1];
                    acc[0][1] = dot8(w1, xa, acc[0][1]);
                    acc[1][1] = dot8(w1, xb, acc[1][1]);
                }
            }
            #pragma unroll
            for (int e = 0; e < 2; e++) {
                if (o0 < NA * NX) {
                    int i = o0 >> 5, l = o0 & 31;
                    s_C[e][i * NXP + l] = acc[e][0];
                } else if (o0 < H2O) {
                    s_na[e][o0 - NA * NX] = sigm_scaled(acc[e][0]);
                }
                if (tid < H2P - 512) {
                    if (o1 < NA * NX) {
                        int i = o1 >> 5, l = o1 & 31;
                        s_C[e][i * NXP + l] = acc[e][1];
                    } else if (o1 < H2O) {
                        s_na[e][o1 - NA * NX] = sigm_scaled(acc[e][1]);
                    }
                }
            }
        }
        __syncthreads();

        // ===== B5: T1 = C@pc ; innov = a - C@pm =====
        #pragma unroll
        for (int r = 0; r < 3; r++) {
            int p = tid + 512 * r;       // 1536 items
            int e = p >= NA * NX, o = p - NA * NX * e, i = o >> 5, l = o & 31;
            float acc = 0.f;
            #pragma unroll
            for (int k = 0; k < NX; k++)
                acc = fmaf(s_C[e][i * NXP + k], s_pc[e][k * NXP + l], acc);
            s_T1[e][i * NXP + l] = acc;
        }
        if (tid >= 464) {
            int idx = tid - 464;         // 48 items
            int e = idx >= NA, i = idx - NA * e;
            float acc = s_a[e][i];
            #pragma unroll
            for (int j = 0; j < NX; j++)
                acc = fmaf(-s_C[e][i * NXP + j], s_pm[e][j], acc);
            s_innov[e][i] = acc;
        }
        __syncthreads();

        // ===== B6: S = T1 @ C^T + diag(na) — 600 items =====
        for (int p = tid; p < 2 * 300; p += 512) {
            int e = p >= 300, pp = p - 300 * e;
            int l, i; tri_decode(pp, l, i);
            float acc = 0.f;
            #pragma unroll
            for (int j = 0; j < NX; j++)
                acc = fmaf(s_T1[e][i * NXP + j], s_C[e][l * NXP + j], acc);
            if (i == l) acc += s_na[e][i];
            s_S[e][i * NA + l] = acc;
            s_S[e][l * NA + i] = acc;
        }
        __syncthreads();

        // ===== B7: per-wave register Gauss-Jordan (wave e solves elem e) =====
        if (tid < 128) {
            int e = tid >> 6, j = tid & 63;
            float r[NA];
            #pragma unroll
            for (int i = 0; i < NA; i++) {
                float v = 0.f;
                if (j < NA) v = s_S[e][i * NA + j];
                else if (j < NA + NX) v = s_T1[e][i * NXP + (j - NA)];
                r[i] = v;
            }
            #pragma unroll
            for (int k = 0; k < NA; k++) {
                float piv = __shfl(r[k], k);
                float ip = 1.0f / piv;
                r[k] *= ip;
                #pragma unroll
                for (int i = 0; i < NA; i++) {
                    if (i == k) continue;
                    float f = __shfl(r[i], k);
                    r[i] = fmaf(-f, r[k], r[i]);
                }
            }
            if (j >= NA && j < NA + NX) {
                #pragma unroll
                for (int i = 0; i < NA; i++) s_Y[e][i * NX + (j - NA)] = r[i];
            }
        }
        __syncthreads();

        // ===== B8: qm = pm + Y^T innov ; qc = psd(pc - Y^T T1) =====
        if (tid < 64) {
            int e = tid >> 5, i = tid & 31;
            float acc = s_pm[e][i];
            #pragma unroll
            for (int q = 0; q < NA; q++)
                acc = fmaf(s_Y[e][q * NX + i], s_innov[e][q], acc);
            s_qm[e][i] = acc;
            unsigned short us = f2h(acc);
            int pi = __shfl_xor((int)us, 1);
            if ((tid & 1) == 0) s_qmh[e][i >> 1] = (uint32)us | ((uint32)pi << 16);
        }
        for (int p = tid; p < 2 * 528; p += 512) {
            int e = p >= 528, pp = p - 528 * e;
            int l, i; tri_decode(pp, l, i);
            float t_il = 0.f, t_li = 0.f;
            #pragma unroll
            for (int q = 0; q < NA; q++) {
                t_il = fmaf(s_Y[e][q * NX + i], s_T1[e][q * NXP + l], t_il);
                t_li = fmaf(s_Y[e][q * NX + l], s_T1[e][q * NXP + i], t_li);
            }
            if (i == l) {
                s_qc[e][i * NXP + i] = s_pc[e][i * NXP + i] - t_il + EPSV;
            } else {
                float v = 0.5f * ((s_pc[e][i * NXP + l] - t_il) + (s_pc[e][l * NXP + i] - t_li));
                s_qc[e][i * NXP + l] = v;
                s_qc[e][l * NXP + i] = v;
            }
        }
        __syncthreads();
    }

    // Epilogue: store final qm/qc (t = NT-1), both elems
    for (int s = tid; s < 2 * (NX + NX * NX); s += 512) {
        int e  = s >= (NX + NX * NX);
        int s2 = s - e * (NX + NX * NX);
        size_t mLast = (size_t)(NT - 1) * NB + b0 + e;
        if (s2 < NX)
            __builtin_nontemporal_store(s_qm[e][s2], out + qmO + mLast * NX + s2);
        else {
            int o = s2 - NX, i = o >> 5, l = o & 31;
            __builtin_nontemporal_store(s_qc[e][i * NXP + l],
                                        out + qcO + mLast * NX * NX + o);
        }
    }
}

// ---------------------------------------------------------------------------
extern "C" void kernel_launch(void* const* d_in, const int* in_sizes, int n_in,
                              void* d_out, int out_size, void* d_ws, size_t ws_size,
                              hipStream_t stream)
{
    const float* u    = (const float*)d_in[0];
    const float* a    = (const float*)d_in[1];
    const float* W1   = (const float*)d_in[2];
    const float* b1   = (const float*)d_in[3];
    const float* W2   = (const float*)d_in[4];
    const float* b2   = (const float*)d_in[5];
    const float* WA   = (const float*)d_in[6];
    const float* bA   = (const float*)d_in[7];
    const float* WB   = (const float*)d_in[8];
    const float* bB   = (const float*)d_in[9];
    const float* WC   = (const float*)d_in[10];
    const float* bC   = (const float*)d_in[11];
    const float* Wnx  = (const float*)d_in[12];
    const float* bnx  = (const float*)d_in[13];
    const float* Wna  = (const float*)d_in[14];
    const float* bna  = (const float*)d_in[15];
    const float* alph = (const float*)d_in[16];

    uint32* wsu = (uint32*)d_ws;
    float* out = (float*)d_out;

    auto pk = [&](const float* src, int O, int K, size_t dst_off, int LDP, int off) {
        int n = O * (K / 2);
        pack_half_off<<<(n + 255) / 256, 256, 0, stream>>>(src, wsu + dst_off, O, K, LDP, off);
    };
    pk(W1,  NH,      NX, OFF_W1, NH,  0);
    pk(W2,  NH,      NH, OFF_W2, NH,  0);
    pk(WA,  NX * NX, NH, OFF_H1, H1P, 0);
    pk(WB,  NX * NU, NH, OFF_H1, H1P, NX * NX);
    pk(Wnx, NX,      NH, OFF_H1, H1P, NX * NX + NX * NU);
    pk(WC,  NA * NX, NH, OFF_H2, H2P, 0);
    pk(Wna, NA,      NH, OFF_H2, H2P, NA * NX);

    pack_bias3<<<(H1O + 255) / 256, 256, 0, stream>>>(bA, NX * NX, bB, NX * NU, bnx, NX,
                                                      (float*)(wsu + OFF_B1));
    pack_bias3<<<(H2O + 255) / 256, 256, 0, stream>>>(bC, NA * NX, bna, NA, nullptr, 0,
                                                      (float*)(wsu + OFF_B2));

    kf_kernel<<<NB / 2, 512, 0, stream>>>(u, a, wsu, b1, b2, alph, out);
}